// Round 6
// baseline (238.489 us; speedup 1.0000x reference)
//
#include <hip/hip_runtime.h>

#define C_LENX 2048
#define Q_LENX 512
#define BATCH  32
#define HDIM   256
#define BH     8192
#define CBLK   32             // c-rows per block: 2 pairs x 16
#define QBLK   32
#define NQT    16
#define TILE_BYTES 49152      // qh 16K + ql 16K + qt 16K, all XOR-swizzled LDS images
#define OFF_QL 16384
#define OFF_QT 32768
#define OFF_EXCH 49152        // 2 pairs x 2048B f32[16][32] S-exchange
#define OFF_SCL  53248        // scale[2][16] f32 + lfin[2][16] f32
#define LDS_TOTAL 53504

typedef __attribute__((ext_vector_type(8))) short bf16x8;
typedef __attribute__((ext_vector_type(4))) float f32x4;

__device__ __forceinline__ unsigned short f2bf(float x) {
    unsigned int u = __float_as_uint(x);
    u += 0x7fffu + ((u >> 16) & 1u);        // round-to-nearest-even
    return (unsigned short)(u >> 16);
}
__device__ __forceinline__ float bf2f(unsigned short h) {
    return __uint_as_float(((unsigned int)h) << 16);
}

// ---------------- prep: fp32 Q -> fused 48KB per-tile blob (exact swizzled LDS image) ----
// qh: byte = q*512 + ((h*2) ^ ((q&7)<<4));  ql same at +16K
// qt: byte = OFF_QT + h*64 + ((q*2) ^ ((h&3)<<4))
__global__ __launch_bounds__(256)
void q_prep(const float* __restrict__ question, unsigned char* __restrict__ blob)
{
    __shared__ unsigned short sHi[QBLK][264];
    const int tid = threadIdx.x;
    const int b  = blockIdx.x >> 4;
    const int t  = blockIdx.x & 15;
    const float* qbase = question + (size_t)(t * QBLK) * BH + b * HDIM;
    unsigned char* tb = blob + (size_t)(b * NQT + t) * TILE_BYTES;

    #pragma unroll
    for (int i = 0; i < 8; ++i) {
        int e  = tid + i * 256;          // float4 cell 0..2047
        int qr = e >> 6;                 // 0..31
        int h4 = (e & 63) << 2;          // 0..252
        float4 x = *reinterpret_cast<const float4*>(qbase + (size_t)qr * BH + h4);
        ushort4 hv, lv;
        hv.x = f2bf(x.x); hv.y = f2bf(x.y); hv.z = f2bf(x.z); hv.w = f2bf(x.w);
        lv.x = f2bf(x.x - bf2f(hv.x)); lv.y = f2bf(x.y - bf2f(hv.y));
        lv.z = f2bf(x.z - bf2f(hv.z)); lv.w = f2bf(x.w - bf2f(hv.w));
        *reinterpret_cast<ushort4*>(&sHi[qr][h4]) = hv;
        unsigned sw = ((unsigned)(h4 * 2)) ^ (((unsigned)qr & 7u) << 4);  // 8B-granule safe
        *reinterpret_cast<ushort4*>(tb + qr * 512 + sw) = hv;
        *reinterpret_cast<ushort4*>(tb + OFF_QL + qr * 512 + sw) = lv;
    }
    __syncthreads();
    #pragma unroll
    for (int i = 0; i < 8; ++i) {
        int e  = tid + i * 256;          // ushort4 cell of qt, 0..2047
        int h  = e >> 3;                 // 0..255
        int q4 = (e & 7) << 2;           // 0..28
        ushort4 v;
        v.x = sHi[q4 + 0][h]; v.y = sHi[q4 + 1][h];
        v.z = sHi[q4 + 2][h]; v.w = sHi[q4 + 3][h];
        unsigned sw = ((unsigned)(q4 * 2)) ^ (((unsigned)h & 3u) << 4);
        *reinterpret_cast<ushort4*>(tb + OFF_QT + h * 64 + sw) = v;
    }
}

// ---------------- main fused attention: h-split wave pairs, 3 blocks/CU ----------------
__global__ __launch_bounds__(256, 3)
void s2s_attn(const float* __restrict__ content,
              const unsigned char* __restrict__ blob,
              const int*   __restrict__ qmask,
              float*       __restrict__ out)
{
    __shared__ __attribute__((aligned(16))) unsigned char sBuf[LDS_TOTAL];

    const int tid  = threadIdx.x;
    const int wid  = tid >> 6;
    const int lane = tid & 63;
    const int lr   = lane & 15;
    const int lg   = lane >> 4;
    const int half = wid & 1;       // h-half: 0 -> h 0..127, 1 -> h 128..255
    const int pair = wid >> 1;      // c-row pair: rows [c0+pair*16, +16)

    // XCD-aware swizzle: 2048 blocks, each XCD owns 4 complete batches
    const int lin = (blockIdx.x & 7) * 256 + (blockIdx.x >> 3);
    const int ct = lin & 63;
    const int b  = lin >> 6;
    const int c0 = ct * CBLK;

    // prologue: reg-stage tile 0 (48KB = 12 segs/thread, linear image)
    bf16x8 stg[12];
    {
        const unsigned char* tb0 = blob + (size_t)(b * NQT) * TILE_BYTES;
        #pragma unroll
        for (int i = 0; i < 12; ++i)
            stg[i] = *reinterpret_cast<const bf16x8*>(tb0 + (wid*12 + i)*1024 + lane*16);
    }

    // content preload: this wave's 16 c-rows x its h-half, hi/lo split (32 regs)
    bf16x8 chi[4], clo[4];
    {
        const float* cbase = content + (size_t)(c0 + pair*16 + lr) * BH + b*HDIM
                             + half*128 + lg*8;
        #pragma unroll
        for (int kc = 0; kc < 4; ++kc) {
            float4 x0 = *reinterpret_cast<const float4*>(cbase + kc*32);
            float4 x1 = *reinterpret_cast<const float4*>(cbase + kc*32 + 4);
            float xs[8] = {x0.x,x0.y,x0.z,x0.w,x1.x,x1.y,x1.z,x1.w};
            bf16x8 hi, lo;
            #pragma unroll
            for (int j = 0; j < 8; ++j) {
                unsigned short hb = f2bf(xs[j]);
                hi[j] = (short)hb;
                lo[j] = (short)f2bf(xs[j] - bf2f(hb));
            }
            chi[kc] = hi; clo[kc] = lo;
        }
    }

    f32x4 acc[8];
    #pragma unroll
    for (int n = 0; n < 8; ++n) { f32x4 z = {0.f,0.f,0.f,0.f}; acc[n] = z; }
    float m_run[4] = {-INFINITY,-INFINITY,-INFINITY,-INFINITY};  // odd waves only
    float l_run[4] = {0.f,0.f,0.f,0.f};

    for (int t = 0; t < NQT; ++t) {
        __syncthreads();                                   // B1: tile t-1 compute done
        #pragma unroll
        for (int i = 0; i < 12; ++i)
            *reinterpret_cast<bf16x8*>(sBuf + (wid*12 + i)*1024 + lane*16) = stg[i];
        __syncthreads();                                   // B2: tile t visible
        if (t + 1 < NQT) {                                 // T14: issue next-tile loads
            const unsigned char* tbn = blob + (size_t)(b*NQT + t + 1) * TILE_BYTES;
            #pragma unroll
            for (int i = 0; i < 12; ++i)
                stg[i] = *reinterpret_cast<const bf16x8*>(tbn + (wid*12 + i)*1024 + lane*16);
        }
        int mk0 = 1, mk1 = 1;
        if (half) {
            mk0 = qmask[b*Q_LENX + t*QBLK + lr];
            mk1 = qmask[b*Q_LENX + t*QBLK + 16 + lr];
        }

        // ---- QK^T over this wave's h-half: 6 independent 4-deep chains ----
        f32x4 zz = {0.f,0.f,0.f,0.f};
        f32x4 s00=zz, s10=zz, s20=zz, s01=zz, s11=zz, s21=zz;
        const unsigned hb = (unsigned)(half * 256);
        const unsigned swz = ((unsigned)lr & 7u) << 4;     // (16+lr)&7 == lr&7
        #pragma unroll
        for (int kc = 0; kc < 4; ++kc) {
            unsigned off = ((unsigned)(hb + kc*64 + lg*16)) ^ swz;
            bf16x8 qh0 = *reinterpret_cast<const bf16x8*>(sBuf + lr*512 + off);
            bf16x8 ql0 = *reinterpret_cast<const bf16x8*>(sBuf + OFF_QL + lr*512 + off);
            bf16x8 qh1 = *reinterpret_cast<const bf16x8*>(sBuf + (16+lr)*512 + off);
            bf16x8 ql1 = *reinterpret_cast<const bf16x8*>(sBuf + OFF_QL + (16+lr)*512 + off);
            s00 = __builtin_amdgcn_mfma_f32_16x16x32_bf16(chi[kc], qh0, s00, 0, 0, 0);
            s10 = __builtin_amdgcn_mfma_f32_16x16x32_bf16(clo[kc], qh0, s10, 0, 0, 0);
            s20 = __builtin_amdgcn_mfma_f32_16x16x32_bf16(chi[kc], ql0, s20, 0, 0, 0);
            s01 = __builtin_amdgcn_mfma_f32_16x16x32_bf16(chi[kc], qh1, s01, 0, 0, 0);
            s11 = __builtin_amdgcn_mfma_f32_16x16x32_bf16(clo[kc], qh1, s11, 0, 0, 0);
            s21 = __builtin_amdgcn_mfma_f32_16x16x32_bf16(chi[kc], ql1, s21, 0, 0, 0);
        }
        f32x4 sacc0 = (s00 + s10) + s20;
        f32x4 sacc1 = (s01 + s11) + s21;

        float* exch = (float*)(sBuf + OFF_EXCH + pair*2048);   // f32[16 c][32 q]
        if (!half) {      // even wave publishes its half-h partial
            #pragma unroll
            for (int r = 0; r < 4; ++r) {
                exch[(lg*4 + r)*32 + lr]      = sacc0[r];
                exch[(lg*4 + r)*32 + 16 + lr] = sacc1[r];
            }
        }
        __syncthreads();                                   // B3: partials visible; qh/ql(t) dead

        unsigned short* sP = (unsigned short*)(sBuf + pair*1024);  // overlay on dead qh rows
        float* scl = (float*)(sBuf + OFF_SCL + pair*64);
        if (half) {       // odd wave: full S, softmax (formulas identical to R4)
            #pragma unroll
            for (int r = 0; r < 4; ++r) {
                sacc0[r] += exch[(lg*4 + r)*32 + lr];
                sacc1[r] += exch[(lg*4 + r)*32 + 16 + lr];
            }
            float p0[4], p1[4], tmax[4];
            #pragma unroll
            for (int r = 0; r < 4; ++r) {
                float v0 = mk0 ? sacc0[r] : -INFINITY;
                float v1 = mk1 ? sacc1[r] : -INFINITY;
                p0[r] = v0; p1[r] = v1;
                tmax[r] = fmaxf(v0, v1);
            }
            #pragma unroll
            for (int off = 1; off < 16; off <<= 1) {
                #pragma unroll
                for (int r = 0; r < 4; ++r)
                    tmax[r] = fmaxf(tmax[r], __shfl_xor(tmax[r], off, 64));
            }
            bool need = false;
            #pragma unroll
            for (int r = 0; r < 4; ++r) need |= (tmax[r] > m_run[r] + 4.0f);
            float scale[4] = {1.f, 1.f, 1.f, 1.f};
            if (__ballot(need)) {          // wave-uniform rescale (T13 defer-max)
                #pragma unroll
                for (int r = 0; r < 4; ++r) {
                    float mnew = fmaxf(m_run[r], tmax[r]);
                    if (mnew != -INFINITY) { scale[r] = __expf(m_run[r] - mnew); m_run[r] = mnew; }
                    l_run[r] *= scale[r];
                }
            }
            unsigned short pb0[4], pb1[4];
            float psum[4];
            #pragma unroll
            for (int r = 0; r < 4; ++r) {
                if (m_run[r] == -INFINITY) {
                    pb0[r] = 0; pb1[r] = 0; psum[r] = 0.f;
                } else {
                    float e0 = __expf(p0[r] - m_run[r]);   // bounded by e^4
                    float e1 = __expf(p1[r] - m_run[r]);
                    pb0[r] = f2bf(e0); pb1[r] = f2bf(e1);
                    psum[r] = bf2f(pb0[r]) + bf2f(pb1[r]); // sum ROUNDED weights
                }
            }
            #pragma unroll
            for (int off = 1; off < 16; off <<= 1) {
                #pragma unroll
                for (int r = 0; r < 4; ++r)
                    psum[r] += __shfl_xor(psum[r], off, 64);
            }
            #pragma unroll
            for (int r = 0; r < 4; ++r)
                l_run[r] += psum[r];
            // publish P (bf16[16 c][32 q], pitch 64B) and per-row scale
            #pragma unroll
            for (int r = 0; r < 4; ++r) {
                int c = lg*4 + r;
                sP[c*32 + lr]      = pb0[r];
                sP[c*32 + 16 + lr] = pb1[r];
            }
            if (lr == 0) {
                #pragma unroll
                for (int r = 0; r < 4; ++r) scl[lg*4 + r] = scale[r];
            }
        }
        __syncthreads();                                   // B4: P + scale visible

        // all waves: rescale acc (scale==1 on deferred tiles), then PV on own h-half
        float s0_ = scl[lg*4+0], s1_ = scl[lg*4+1], s2_ = scl[lg*4+2], s3_ = scl[lg*4+3];
        if (__ballot(s0_ != 1.f || s1_ != 1.f || s2_ != 1.f || s3_ != 1.f)) {
            #pragma unroll
            for (int n = 0; n < 8; ++n) {
                acc[n][0] *= s0_; acc[n][1] *= s1_;
                acc[n][2] *= s2_; acc[n][3] *= s3_;
            }
        }
        bf16x8 pfrag = *reinterpret_cast<const bf16x8*>(sBuf + pair*1024 + lr*64 + lg*16);
        #pragma unroll
        for (int n = 0; n < 8; ++n) {
            int h = half*128 + n*16 + lr;
            bf16x8 vfrag = *reinterpret_cast<const bf16x8*>(
                sBuf + OFF_QT + h*64 + (((unsigned)(lg*16)) ^ (((unsigned)h & 3u) << 4)));
            acc[n] = __builtin_amdgcn_mfma_f32_16x16x32_bf16(pfrag, vfrag, acc[n], 0, 0, 0);
        }
    }

    // ---- epilogue: odd waves publish l_run; everyone normalizes & stores ----
    float* lfin = (float*)(sBuf + OFF_SCL + 128 + pair*64);
    if (half && lr == 0) {
        #pragma unroll
        for (int r = 0; r < 4; ++r) lfin[lg*4 + r] = l_run[r];
    }
    __syncthreads();
    float rinv[4];
    #pragma unroll
    for (int r = 0; r < 4; ++r) rinv[r] = 1.f / lfin[lg*4 + r];
    float* obase = out + (size_t)(c0 + pair*16) * BH + b*HDIM + half*128;
    #pragma unroll
    for (int n = 0; n < 8; ++n) {
        #pragma unroll
        for (int r = 0; r < 4; ++r)
            obase[(size_t)(lg*4 + r) * BH + n*16 + lr] = acc[n][r] * rinv[r];
    }
}

extern "C" void kernel_launch(void* const* d_in, const int* in_sizes, int n_in,
                              void* d_out, int out_size, void* d_ws, size_t ws_size,
                              hipStream_t stream) {
    const float* content  = (const float*)d_in[0];
    const float* question = (const float*)d_in[1];
    const int*   mask     = (const int*)d_in[2];
    float*       out      = (float*)d_out;

    unsigned char* blob = (unsigned char*)d_ws;   // 512 tiles * 48KB = 24 MB

    q_prep<<<BATCH * NQT, 256, 0, stream>>>(question, blob);
    s2s_attn<<<C_LENX / CBLK * BATCH, 256, 0, stream>>>(content, blob, mask, out);
}

// Round 7
// 120.805 us; speedup vs baseline: 1.9742x; 1.9742x over previous
//
#include <hip/hip_runtime.h>

#define C_LENX 2048
#define Q_LENX 512
#define BATCH  32
#define HDIM   256
#define BH     8192
#define CBLK   64
#define QBLK   32
#define NQT    16
#define NWAVES 4
#define QH_PITCH 264
#define QT_PITCH 40
#define P_PITCH  40
#define TILE_ELEMS (QBLK*HDIM)

typedef __attribute__((ext_vector_type(8))) short bf16x8;
typedef __attribute__((ext_vector_type(4))) float f32x4;

__device__ __forceinline__ unsigned short f2bf(float x) {
    unsigned int u = __float_as_uint(x);
    u += 0x7fffu + ((u >> 16) & 1u);        // round-to-nearest-even
    return (unsigned short)(u >> 16);
}
__device__ __forceinline__ float bf2f(unsigned short h) {
    return __uint_as_float(((unsigned int)h) << 16);
}

// ---------------- prep: fp32 Q -> bf16 hi/lo blobs + transposed-hi blob (R4) -------------
__global__ __launch_bounds__(256)
void q_prep(const float* __restrict__ question,
            unsigned short* __restrict__ qh,
            unsigned short* __restrict__ ql,
            unsigned short* __restrict__ qt)
{
    __shared__ unsigned short sHi[QBLK][QH_PITCH];
    const int tid = threadIdx.x;
    const int b  = blockIdx.x >> 4;
    const int t  = blockIdx.x & 15;
    const int q0 = t * QBLK;
    const float* qbase = question + (size_t)q0 * BH + b * HDIM;
    const size_t blob = (size_t)(b * NQT + t) * TILE_ELEMS;

    #pragma unroll
    for (int i = 0; i < 8; ++i) {
        int e  = tid + i * 256;
        int qr = e >> 6;
        int h4 = (e & 63) << 2;
        float4 x = *reinterpret_cast<const float4*>(qbase + (size_t)qr * BH + h4);
        ushort4 hv, lv;
        hv.x = f2bf(x.x); hv.y = f2bf(x.y); hv.z = f2bf(x.z); hv.w = f2bf(x.w);
        lv.x = f2bf(x.x - bf2f(hv.x)); lv.y = f2bf(x.y - bf2f(hv.y));
        lv.z = f2bf(x.z - bf2f(hv.z)); lv.w = f2bf(x.w - bf2f(hv.w));
        *reinterpret_cast<ushort4*>(&sHi[qr][h4]) = hv;
        *reinterpret_cast<ushort4*>(qh + blob + (size_t)qr * HDIM + h4) = hv;
        *reinterpret_cast<ushort4*>(ql + blob + (size_t)qr * HDIM + h4) = lv;
    }
    __syncthreads();
    #pragma unroll
    for (int i = 0; i < 8; ++i) {
        int e  = tid + i * 256;
        int h  = e >> 3;
        int q4 = (e & 7) << 2;
        ushort4 v;
        v.x = sHi[q4 + 0][h]; v.y = sHi[q4 + 1][h];
        v.z = sHi[q4 + 2][h]; v.w = sHi[q4 + 3][h];
        *reinterpret_cast<ushort4*>(qt + blob + (size_t)h * QBLK + q4) = v;
    }
}

// ---------------- main fused attention: swapped QK^T, per-lane softmax -------------------
__global__ __launch_bounds__(256, 2)
void s2s_attn(const float* __restrict__ content,
              const unsigned short* __restrict__ qh_blob,
              const unsigned short* __restrict__ ql_blob,
              const unsigned short* __restrict__ qt_blob,
              const int*   __restrict__ qmask,
              float*       __restrict__ out)
{
    __shared__ unsigned short sQh[QBLK][QH_PITCH];
    __shared__ unsigned short sQl[QBLK][QH_PITCH];
    __shared__ unsigned short sQt[HDIM][QT_PITCH];
    __shared__ unsigned short sP [NWAVES][16][P_PITCH];
    __shared__ unsigned sMaskW[NQT];

    const int tid  = threadIdx.x;
    const int wid  = tid >> 6;
    const int lane = tid & 63;
    const int lr   = lane & 15;
    const int lg   = lane >> 4;

    // XCD-aware swizzle: each XCD owns 4 complete batches (blob L2 locality)
    const int lin = (blockIdx.x & 7) * 128 + (blockIdx.x >> 3);
    const int ct = lin & 31;
    const int b  = lin >> 5;
    const int c0 = ct * CBLK;

    // pack mask into one 32-bit word per q-tile via wave ballots
    #pragma unroll
    for (int j = 0; j < 2; ++j) {
        int qb = (wid * 2 + j) * 64;
        unsigned long long bal = __ballot(qmask[b * Q_LENX + qb + lane] != 0);
        if (lane == 0) {
            sMaskW[(qb >> 5)]     = (unsigned)bal;
            sMaskW[(qb >> 5) + 1] = (unsigned)(bal >> 32);
        }
    }

    // prologue: issue tile-0 staging loads
    bf16x8 stg[12];
    {
        const size_t blob0 = (size_t)(b * NQT + 0) * TILE_ELEMS;
        #pragma unroll
        for (int i = 0; i < 4; ++i) {
            int e = tid + i * 256;
            stg[i]     = *reinterpret_cast<const bf16x8*>(qh_blob + blob0 + (size_t)e * 8);
            stg[4 + i] = *reinterpret_cast<const bf16x8*>(ql_blob + blob0 + (size_t)e * 8);
            stg[8 + i] = *reinterpret_cast<const bf16x8*>(qt_blob + blob0 + (size_t)e * 8);
        }
    }

    // preload this wave's 16 content rows as hi/lo bf16 fragments
    // (lane l&15 = c-row, l>>4 = h-subblock: valid as BOTH A-frag and B-frag layout)
    bf16x8 chi[8], clo[8];
    {
        const float* cbase = content + (size_t)(c0 + wid*16 + lr) * BH + b*HDIM + lg*8;
        #pragma unroll
        for (int kc = 0; kc < 8; ++kc) {
            float4 x0 = *reinterpret_cast<const float4*>(cbase + kc*32);
            float4 x1 = *reinterpret_cast<const float4*>(cbase + kc*32 + 4);
            float xs[8] = {x0.x,x0.y,x0.z,x0.w,x1.x,x1.y,x1.z,x1.w};
            bf16x8 hi, lo;
            #pragma unroll
            for (int j = 0; j < 8; ++j) {
                unsigned short hb = f2bf(xs[j]);
                hi[j] = (short)hb;
                lo[j] = (short)f2bf(xs[j] - bf2f(hb));
            }
            chi[kc] = hi; clo[kc] = lo;
        }
    }

    f32x4 acc[16];
    #pragma unroll
    for (int n = 0; n < 16; ++n) { f32x4 z = {0.f,0.f,0.f,0.f}; acc[n] = z; }
    float m_run = -INFINITY;   // softmax state for c-row lr (replicated on 4 lanes)
    float l_run = 0.f;

    for (int t = 0; t < NQT; ++t) {
        __syncthreads();   // B1: previous tile consumed (also publishes sMaskW at t=0)
        #pragma unroll
        for (int i = 0; i < 4; ++i) {
            int e  = tid + i * 256;
            int qr = e >> 5;
            int h8 = (e & 31) << 3;
            *reinterpret_cast<bf16x8*>(&sQh[qr][h8]) = stg[i];
            *reinterpret_cast<bf16x8*>(&sQl[qr][h8]) = stg[4 + i];
            int h  = e >> 2;
            int q8 = (e & 3) << 3;
            *reinterpret_cast<bf16x8*>(&sQt[h][q8]) = stg[8 + i];
        }
        __syncthreads();   // B2: tile t visible
        if (t + 1 < NQT) {  // T14: issue next tile's loads; latency hides under compute
            const size_t blobn = (size_t)(b * NQT + t + 1) * TILE_ELEMS;
            #pragma unroll
            for (int i = 0; i < 4; ++i) {
                int e = tid + i * 256;
                stg[i]     = *reinterpret_cast<const bf16x8*>(qh_blob + blobn + (size_t)e * 8);
                stg[4 + i] = *reinterpret_cast<const bf16x8*>(ql_blob + blobn + (size_t)e * 8);
                stg[8 + i] = *reinterpret_cast<const bf16x8*>(qt_blob + blobn + (size_t)e * 8);
            }
        }
        const unsigned mw = sMaskW[t];   // broadcast read

        // ---- swapped QK^T: S^T[q][c] = mfma(A=question, B=content); 6 independent chains
        f32x4 zz = {0.f,0.f,0.f,0.f};
        f32x4 s00=zz, s10=zz, s20=zz, s01=zz, s11=zz, s21=zz;
        #pragma unroll
        for (int kc = 0; kc < 8; ++kc) {
            bf16x8 qh0 = *reinterpret_cast<bf16x8*>(&sQh[lr]   [kc*32 + lg*8]);
            bf16x8 ql0 = *reinterpret_cast<bf16x8*>(&sQl[lr]   [kc*32 + lg*8]);
            bf16x8 qh1 = *reinterpret_cast<bf16x8*>(&sQh[16+lr][kc*32 + lg*8]);
            bf16x8 ql1 = *reinterpret_cast<bf16x8*>(&sQl[16+lr][kc*32 + lg*8]);
            s00 = __builtin_amdgcn_mfma_f32_16x16x32_bf16(qh0, chi[kc], s00, 0, 0, 0);
            s10 = __builtin_amdgcn_mfma_f32_16x16x32_bf16(qh0, clo[kc], s10, 0, 0, 0);
            s20 = __builtin_amdgcn_mfma_f32_16x16x32_bf16(ql0, chi[kc], s20, 0, 0, 0);
            s01 = __builtin_amdgcn_mfma_f32_16x16x32_bf16(qh1, chi[kc], s01, 0, 0, 0);
            s11 = __builtin_amdgcn_mfma_f32_16x16x32_bf16(qh1, clo[kc], s11, 0, 0, 0);
            s21 = __builtin_amdgcn_mfma_f32_16x16x32_bf16(ql1, chi[kc], s21, 0, 0, 0);
        }
        f32x4 sacc0 = (s00 + s10) + s20;   // rows q=lg*4+r,     col c=lr
        f32x4 sacc1 = (s01 + s11) + s21;   // rows q=16+lg*4+r,  col c=lr

        // ---- per-lane softmax for c-row lr (reduce over 4 lanes sharing lr) ----
        float p[8];
        float tmax = -INFINITY;
        #pragma unroll
        for (int r = 0; r < 4; ++r) {
            float v0 = ((mw >> (lg*4 + r))      & 1u) ? sacc0[r] : -INFINITY;
            float v1 = ((mw >> (16 + lg*4 + r)) & 1u) ? sacc1[r] : -INFINITY;
            p[r] = v0; p[4 + r] = v1;
            tmax = fmaxf(tmax, fmaxf(v0, v1));
        }
        tmax = fmaxf(tmax, __shfl_xor(tmax, 16, 64));
        tmax = fmaxf(tmax, __shfl_xor(tmax, 32, 64));

        if (__ballot(tmax > m_run + 4.0f)) {   // T13 defer-max, wave-uniform
            float mnew = fmaxf(m_run, tmax);
            float scale = 1.f;
            if (mnew != -INFINITY) { scale = __expf(m_run - mnew); m_run = mnew; }
            l_run *= scale;
            // broadcast scale into acc domain (acc row c = lg*4+r held by this lane)
            float sc0 = __shfl(scale, lg*4 + 0, 16);
            float sc1 = __shfl(scale, lg*4 + 1, 16);
            float sc2 = __shfl(scale, lg*4 + 2, 16);
            float sc3 = __shfl(scale, lg*4 + 3, 16);
            #pragma unroll
            for (int n = 0; n < 16; ++n) {
                acc[n][0] *= sc0; acc[n][1] *= sc1;
                acc[n][2] *= sc2; acc[n][3] *= sc3;
            }
        }

        unsigned short pb[8];
        float psum = 0.f;
        if (m_run == -INFINITY) {
            #pragma unroll
            for (int i = 0; i < 8; ++i) pb[i] = 0;
        } else {
            #pragma unroll
            for (int i = 0; i < 8; ++i) {
                float e = __expf(p[i] - m_run);    // bounded by e^4
                pb[i] = f2bf(e);
                psum += bf2f(pb[i]);               // sum ROUNDED weights
            }
        }
        psum += __shfl_xor(psum, 16, 64);
        psum += __shfl_xor(psum, 32, 64);
        l_run += psum;

        // ---- P^T -> sP[wid][c][q] (wave-private; 2 x ds_write_b64) ----
        {
            ushort4 w0, w1;
            w0.x = pb[0]; w0.y = pb[1]; w0.z = pb[2]; w0.w = pb[3];
            w1.x = pb[4]; w1.y = pb[5]; w1.z = pb[6]; w1.w = pb[7];
            *reinterpret_cast<ushort4*>(&sP[wid][lr][lg*4])      = w0;  // q = lg*4..+3
            *reinterpret_cast<ushort4*>(&sP[wid][lr][16 + lg*4]) = w1;  // q = 16+lg*4..+3
        }
        bf16x8 pfrag = *reinterpret_cast<bf16x8*>(&sP[wid][lr][lg*8]);  // A[c=lr][q-block]

        // ---- PV: acc[16 c x 256 h] += P(16x32) * Q(32x256) (unchanged from R4) ----
        #pragma unroll
        for (int n = 0; n < 16; ++n) {
            bf16x8 vfrag = *reinterpret_cast<bf16x8*>(&sQt[n*16 + lr][lg*8]);
            acc[n] = __builtin_amdgcn_mfma_f32_16x16x32_bf16(pfrag, vfrag, acc[n], 0, 0, 0);
        }
    }

    // ---- epilogue: broadcast l_run (per c=lr) into acc domain, normalize, store ----
    float linv = 1.f / l_run;
    float rinv[4];
    rinv[0] = __shfl(linv, lg*4 + 0, 16);
    rinv[1] = __shfl(linv, lg*4 + 1, 16);
    rinv[2] = __shfl(linv, lg*4 + 2, 16);
    rinv[3] = __shfl(linv, lg*4 + 3, 16);
    float* obase = out + (size_t)(c0 + wid*16) * BH + b*HDIM;
    #pragma unroll
    for (int n = 0; n < 16; ++n) {
        #pragma unroll
        for (int r = 0; r < 4; ++r)
            obase[(size_t)(lg*4 + r) * BH + n*16 + lr] = acc[n][r] * rinv[r];
    }
}

extern "C" void kernel_launch(void* const* d_in, const int* in_sizes, int n_in,
                              void* d_out, int out_size, void* d_ws, size_t ws_size,
                              hipStream_t stream) {
    const float* content  = (const float*)d_in[0];
    const float* question = (const float*)d_in[1];
    const int*   mask     = (const int*)d_in[2];
    float*       out      = (float*)d_out;

    unsigned short* qh = (unsigned short*)d_ws;
    unsigned short* ql = qh + (size_t)BATCH * NQT * TILE_ELEMS;
    unsigned short* qt = ql + (size_t)BATCH * NQT * TILE_ELEMS;

    q_prep<<<BATCH * NQT, 256, 0, stream>>>(question, qh, ql, qt);
    s2s_attn<<<C_LENX / CBLK * BATCH, 256, 0, stream>>>(content, qh, ql, qt, mask, out);
}

// Round 8
// 94.788 us; speedup vs baseline: 2.5160x; 1.2745x over previous
//
#include <hip/hip_runtime.h>

#define C_LENX 2048
#define Q_LENX 512
#define BATCH  32
#define HDIM   256
#define BH     8192
#define CBLK   64
#define QBLK   32
#define NQT    16
#define NWAVES 4
#define TILE_BYTES 32768      // qf 16K (fp16[32][256], swz) + qt 16K (fp16[256][32], swz)
#define OFF_QT 16384

typedef __attribute__((ext_vector_type(8))) _Float16 f16x8;
typedef __attribute__((ext_vector_type(4))) float f32x4;

__device__ __forceinline__ unsigned short f2h_bits(float x) {
    union { _Float16 h; unsigned short u; } cv;
    cv.h = (_Float16)x;                     // RTNE
    return cv.u;
}
__device__ __forceinline__ float h2f_bits(unsigned short u) {
    union { unsigned short u; _Float16 h; } cv;
    cv.u = u;
    return (float)cv.h;
}

// async global->LDS, 16B per lane, wave-uniform LDS base + lane*16
__device__ __forceinline__ void stage16(const void* gsrc, void* ldst) {
    __builtin_amdgcn_global_load_lds(
        (const __attribute__((address_space(1))) unsigned int*)gsrc,
        (__attribute__((address_space(3))) unsigned int*)ldst, 16, 0, 0);
}

// ---------------- prep: fp32 Q -> fp16 blob (exact swizzled LDS images) ----------------
// qf: row q (512B); 16B chunk c at byte q*512 + 16*(c ^ (q&7))     [holds Q[q][8c..8c+7]]
// qt: chunk m = h*4 + qc (qc = q/8) at byte OFF_QT + 16*(m ^ ((m>>3)&7))
__global__ __launch_bounds__(256)
void q_prep(const float* __restrict__ question, unsigned char* __restrict__ blob)
{
    __shared__ unsigned short sHf[QBLK][264];
    const int tid = threadIdx.x;
    const int b  = blockIdx.x >> 4;
    const int t  = blockIdx.x & 15;
    const float* qbase = question + (size_t)(t * QBLK) * BH + b * HDIM;
    unsigned char* tb = blob + (size_t)(b * NQT + t) * TILE_BYTES;

    #pragma unroll
    for (int i = 0; i < 8; ++i) {
        int e  = tid + i * 256;          // float4 cell 0..2047
        int qr = e >> 6;                 // 0..31
        int h4 = (e & 63) << 2;          // 0..252
        float4 x = *reinterpret_cast<const float4*>(qbase + (size_t)qr * BH + h4);
        ushort4 hv;
        hv.x = f2h_bits(x.x); hv.y = f2h_bits(x.y);
        hv.z = f2h_bits(x.z); hv.w = f2h_bits(x.w);
        *reinterpret_cast<ushort4*>(&sHf[qr][h4]) = hv;
        int c = h4 >> 3;                 // 16B chunk within row
        *reinterpret_cast<ushort4*>(tb + qr * 512 + ((c ^ (qr & 7)) << 4) + ((h4 & 7) << 1)) = hv;
    }
    __syncthreads();
    #pragma unroll
    for (int i = 0; i < 8; ++i) {
        int e  = tid + i * 256;          // ushort4 cell of qt, 0..2047
        int h  = e >> 3;                 // 0..255
        int q4 = (e & 7) << 2;           // 0..28
        ushort4 v;
        v.x = sHf[q4 + 0][h]; v.y = sHf[q4 + 1][h];
        v.z = sHf[q4 + 2][h]; v.w = sHf[q4 + 3][h];
        int m  = h * 4 + (q4 >> 3);
        int ms = m ^ ((m >> 3) & 7);
        *reinterpret_cast<ushort4*>(tb + OFF_QT + (ms << 4) + ((q4 & 4) << 1)) = v;
    }
}

// ---------------- main: fp16 2-term QK^T, gll double-buffer, reg-P PV ----------------
__global__ __launch_bounds__(256, 2)
void s2s_attn(const float* __restrict__ content,
              const unsigned char* __restrict__ blob,
              const int*   __restrict__ qmask,
              float*       __restrict__ out)
{
    __shared__ __attribute__((aligned(16))) unsigned char sBuf[2 * TILE_BYTES];

    const int tid  = threadIdx.x;
    const int wid  = tid >> 6;
    const int lane = tid & 63;
    const int lr   = lane & 15;
    const int lg   = lane >> 4;

    // XCD-aware swizzle: each XCD owns 4 complete batches (blob L2 locality)
    const int lin = (blockIdx.x & 7) * 128 + (blockIdx.x >> 3);
    const int ct = lin & 31;
    const int b  = lin >> 5;
    const int c0 = ct * CBLK;

    // prologue: DMA tile 0 into buffer 0 (32 segs of 1KB; 8 per wave)
    {
        const unsigned char* tb0 = blob + (size_t)(b * NQT) * TILE_BYTES;
        #pragma unroll
        for (int j = 0; j < 8; ++j) {
            int seg = wid * 8 + j;
            stage16(tb0 + seg * 1024 + lane * 16, sBuf + seg * 1024);
        }
    }

    // content preload: 16 c-rows as fp16 hi/lo fragments (A/B-frag layout: row=lr, k=lg*8)
    f16x8 chi[8], clo[8];
    {
        const float* cbase = content + (size_t)(c0 + wid*16 + lr) * BH + b*HDIM + lg*8;
        #pragma unroll
        for (int kc = 0; kc < 8; ++kc) {
            float4 x0 = *reinterpret_cast<const float4*>(cbase + kc*32);
            float4 x1 = *reinterpret_cast<const float4*>(cbase + kc*32 + 4);
            float xs[8] = {x0.x,x0.y,x0.z,x0.w,x1.x,x1.y,x1.z,x1.w};
            #pragma unroll
            for (int j = 0; j < 8; ++j) {
                _Float16 hi = (_Float16)xs[j];
                chi[kc][j] = hi;
                clo[kc][j] = (_Float16)(xs[j] - (float)hi);
            }
        }
    }

    f32x4 acc[16];
    #pragma unroll
    for (int n = 0; n < 16; ++n) { f32x4 z = {0.f,0.f,0.f,0.f}; acc[n] = z; }
    float m_run = -INFINITY;   // softmax state for c-row lr (replicated on 4 lanes)
    float l_run = 0.f;

    __syncthreads();           // tile 0 DMA drained + visible

    for (int t = 0; t < NQT; ++t) {
        const unsigned char* qf = sBuf + (t & 1) * TILE_BYTES;
        const unsigned char* qt = qf + OFF_QT;

        // T3 2-phase: issue next tile's DMA into the other buffer, compute, one barrier
        if (t + 1 < NQT) {
            const unsigned char* tbn = blob + (size_t)(b * NQT + t + 1) * TILE_BYTES;
            unsigned char* db = sBuf + ((t + 1) & 1) * TILE_BYTES;
            #pragma unroll
            for (int j = 0; j < 8; ++j) {
                int seg = wid * 8 + j;
                stage16(tbn + seg * 1024 + lane * 16, db + seg * 1024);
            }
        }
        const unsigned mw = (unsigned)__ballot(qmask[b * Q_LENX + t * QBLK + (lane & 31)] != 0);

        // ---- swapped QK^T: S^T = mfma(A=Q, B=C); 4 independent chains, fp16 2-term ----
        f32x4 zz = {0.f,0.f,0.f,0.f};
        f32x4 s00=zz, s10=zz, s01=zz, s11=zz;
        const unsigned swz = (unsigned)(lr & 7);   // (16+lr)&7 == lr&7
        __builtin_amdgcn_s_setprio(1);
        #pragma unroll
        for (int kc = 0; kc < 8; ++kc) {
            unsigned off = (unsigned)((kc*4 + lg) ^ swz) << 4;
            f16x8 qf0 = *reinterpret_cast<const f16x8*>(qf + lr*512 + off);
            f16x8 qf1 = *reinterpret_cast<const f16x8*>(qf + (16+lr)*512 + off);
            s00 = __builtin_amdgcn_mfma_f32_16x16x32_f16(qf0, chi[kc], s00, 0, 0, 0);
            s10 = __builtin_amdgcn_mfma_f32_16x16x32_f16(qf0, clo[kc], s10, 0, 0, 0);
            s01 = __builtin_amdgcn_mfma_f32_16x16x32_f16(qf1, chi[kc], s01, 0, 0, 0);
            s11 = __builtin_amdgcn_mfma_f32_16x16x32_f16(qf1, clo[kc], s11, 0, 0, 0);
        }
        __builtin_amdgcn_s_setprio(0);
        f32x4 sacc0 = s00 + s10;   // rows q=lg*4+r,    col c=lr
        f32x4 sacc1 = s01 + s11;   // rows q=16+lg*4+r, col c=lr

        // ---- per-lane softmax for c-row lr (reduce over lanes lr, lr+16, lr+32, lr+48) ----
        float p[8];
        float tmax = -INFINITY;
        #pragma unroll
        for (int r = 0; r < 4; ++r) {
            float v0 = ((mw >> (lg*4 + r))      & 1u) ? sacc0[r] : -INFINITY;
            float v1 = ((mw >> (16 + lg*4 + r)) & 1u) ? sacc1[r] : -INFINITY;
            p[r] = v0; p[4 + r] = v1;
            tmax = fmaxf(tmax, fmaxf(v0, v1));
        }
        tmax = fmaxf(tmax, __shfl_xor(tmax, 16, 64));
        tmax = fmaxf(tmax, __shfl_xor(tmax, 32, 64));

        if (__ballot(tmax > m_run + 4.0f)) {   // T13 defer-max, wave-uniform
            float mnew = fmaxf(m_run, tmax);
            float scale = 1.f;
            if (mnew != -INFINITY) { scale = __expf(m_run - mnew); m_run = mnew; }
            l_run *= scale;
            float sc0 = __shfl(scale, lg*4 + 0, 16);
            float sc1 = __shfl(scale, lg*4 + 1, 16);
            float sc2 = __shfl(scale, lg*4 + 2, 16);
            float sc3 = __shfl(scale, lg*4 + 3, 16);
            #pragma unroll
            for (int n = 0; n < 16; ++n) {
                acc[n][0] *= sc0; acc[n][1] *= sc1;
                acc[n][2] *= sc2; acc[n][3] *= sc3;
            }
        }

        unsigned short pb[8];
        float psum = 0.f;
        if (m_run == -INFINITY) {
            #pragma unroll
            for (int i = 0; i < 8; ++i) pb[i] = 0;
        } else {
            #pragma unroll
            for (int i = 0; i < 8; ++i) {
                float e = __expf(p[i] - m_run);    // bounded by e^4
                pb[i] = f2h_bits(e);
                psum += h2f_bits(pb[i]);           // sum ROUNDED weights
            }
        }
        psum += __shfl_xor(psum, 16, 64);
        psum += __shfl_xor(psum, 32, 64);
        l_run += psum;

        // ---- P redistribution in-register (no LDS): source lane (lg_s,lr) holds
        //      d0={q=4lg_s,+1} d1={+2,+3} d2={16+4lg_s,+1} d3={+2,+3};
        //      target lane (lg_t,lr) A-frag needs q = 8*lg_t .. +7
        unsigned d0 = (unsigned)pb[0] | ((unsigned)pb[1] << 16);
        unsigned d1 = (unsigned)pb[2] | ((unsigned)pb[3] << 16);
        unsigned d2 = (unsigned)pb[4] | ((unsigned)pb[5] << 16);
        unsigned d3 = (unsigned)pb[6] | ((unsigned)pb[7] << 16);
        int srcA = ((2*lg) & 3) * 16 + lr;
        int srcB = srcA + 16;
        bool hi = (lg >= 2);
        unsigned a0 = (unsigned)__shfl((int)d0, srcA, 64);
        unsigned a1 = (unsigned)__shfl((int)d1, srcA, 64);
        unsigned a2 = (unsigned)__shfl((int)d2, srcA, 64);
        unsigned a3 = (unsigned)__shfl((int)d3, srcA, 64);
        unsigned b0 = (unsigned)__shfl((int)d0, srcB, 64);
        unsigned b1 = (unsigned)__shfl((int)d1, srcB, 64);
        unsigned b2 = (unsigned)__shfl((int)d2, srcB, 64);
        unsigned b3 = (unsigned)__shfl((int)d3, srcB, 64);
        union { unsigned u[4]; f16x8 v; } pu;
        pu.u[0] = hi ? a2 : a0;
        pu.u[1] = hi ? a3 : a1;
        pu.u[2] = hi ? b2 : b0;
        pu.u[3] = hi ? b3 : b1;
        f16x8 pfrag = pu.v;

        // ---- PV: acc[16 c x 256 h] += P(16x32) * Q(32x256), fp16 ----
        __builtin_amdgcn_s_setprio(1);
        #pragma unroll
        for (int n = 0; n < 16; ++n) {
            int h = n*16 + lr;
            int m = h*4 + lg;
            int ms = m ^ ((m >> 3) & 7);
            f16x8 vfrag = *reinterpret_cast<const f16x8*>(qt + (ms << 4));
            acc[n] = __builtin_amdgcn_mfma_f32_16x16x32_f16(pfrag, vfrag, acc[n], 0, 0, 0);
        }
        __builtin_amdgcn_s_setprio(0);

        __syncthreads();   // all waves done with tile t; next tile's DMA drained
    }

    // ---- epilogue: broadcast 1/l_run (per c=lr) into acc domain, normalize, store ----
    float linv = 1.f / l_run;
    float rinv[4];
    rinv[0] = __shfl(linv, lg*4 + 0, 16);
    rinv[1] = __shfl(linv, lg*4 + 1, 16);
    rinv[2] = __shfl(linv, lg*4 + 2, 16);
    rinv[3] = __shfl(linv, lg*4 + 3, 16);
    float* obase = out + (size_t)(c0 + wid*16) * BH + b*HDIM;
    #pragma unroll
    for (int n = 0; n < 16; ++n) {
        #pragma unroll
        for (int r = 0; r < 4; ++r)
            obase[(size_t)(lg*4 + r) * BH + n*16 + lr] = acc[n][r] * rinv[r];
    }
}

extern "C" void kernel_launch(void* const* d_in, const int* in_sizes, int n_in,
                              void* d_out, int out_size, void* d_ws, size_t ws_size,
                              hipStream_t stream) {
    const float* content  = (const float*)d_in[0];
    const float* question = (const float*)d_in[1];
    const int*   mask     = (const int*)d_in[2];
    float*       out      = (float*)d_out;

    unsigned char* blob = (unsigned char*)d_ws;   // 512 tiles * 32KB = 16 MB

    q_prep<<<BATCH * NQT, 256, 0, stream>>>(question, blob);
    s2s_attn<<<C_LENX / CBLK * BATCH, 256, 0, stream>>>(content, blob, mask, out);
}